// Round 1
// baseline (644.914 us; speedup 1.0000x reference)
//
#include <hip/hip_runtime.h>

typedef _Float16 f16;
typedef f16 f16x8 __attribute__((ext_vector_type(8)));
typedef f16 f16x4 __attribute__((ext_vector_type(4)));
typedef float f32x4 __attribute__((ext_vector_type(4)));

#define GLD_LDS16(g, l) __builtin_amdgcn_global_load_lds( \
    (const __attribute__((address_space(1))) void*)(g),   \
    (__attribute__((address_space(3))) void*)(l), 16, 0, 0)

// ---------------------------------------------------------------------------
// cast x (f32) -> fp16, contiguous
__global__ __launch_bounds__(256) void cast_x_kernel(const float* __restrict__ x,
                                                     f16* __restrict__ xh) {
    long i = ((long)blockIdx.x * 256 + threadIdx.x) * 8;
    float4 a = *(const float4*)&x[i];
    float4 b = *(const float4*)&x[i + 4];
    f16x8 v;
    v[0] = (f16)a.x; v[1] = (f16)a.y; v[2] = (f16)a.z; v[3] = (f16)a.w;
    v[4] = (f16)b.x; v[5] = (f16)b.y; v[6] = (f16)b.z; v[7] = (f16)b.w;
    *(f16x8*)&xh[i] = v;
}

// cast + transpose weights: W[i][d][o] f32 -> WT[i][o][d] fp16 (64x64 tiles)
__global__ __launch_bounds__(256) void cast_transpose_w(const float* __restrict__ W,
                                                        f16* __restrict__ WT) {
    __shared__ float tile[64][65];
    const int iz = blockIdx.z;
    const int d0 = blockIdx.y * 64;
    const int o0 = blockIdx.x * 64;
    const float* Wi = W + (long)iz * 1024 * 1024;
    f16* WTi = WT + (long)iz * 1024 * 1024;
    const int t = threadIdx.x;
#pragma unroll
    for (int j = 0; j < 4; ++j) {
        int idx = t + j * 256;          // 1024 float4 chunks
        int r = idx >> 4;               // 0..63 (d)
        int c4 = (idx & 15) * 4;        // 0..60 (o)
        float4 v = *(const float4*)&Wi[(long)(d0 + r) * 1024 + o0 + c4];
        tile[r][c4 + 0] = v.x; tile[r][c4 + 1] = v.y;
        tile[r][c4 + 2] = v.z; tile[r][c4 + 3] = v.w;
    }
    __syncthreads();
#pragma unroll
    for (int j = 0; j < 2; ++j) {
        int idx = t + j * 256;          // 512 chunks of 8 halfs
        int ol = idx >> 3;              // 0..63 (o)
        int c8 = (idx & 7) * 8;         // 0..56 (d)
        f16x8 v;
#pragma unroll
        for (int e = 0; e < 8; ++e) v[e] = (f16)tile[c8 + e][ol];
        *(f16x8*)&WTi[(long)(o0 + ol) * 1024 + d0 + c8] = v;
    }
}

// ---------------------------------------------------------------------------
// 128x128 tile gemm_bt (m97 structure): C = A * B^T, A[m][k], B[n][k] row-major.
// MODE 0: C fp16 row-major (C + z*sC, stride ldc)
// MODE 1: C fp16 written as batched V^T: row m=(b,s), col o -> C[b*2^21 + o*2048 + s]
// MODE 2: C f32 row-major
template <int MODE>
__global__ __launch_bounds__(256)
void gemm_bt(const f16* __restrict__ A, const f16* __restrict__ B,
             void* __restrict__ Cv,
             int lda, int ldb, int K,
             long sA, long sB, long sC, int ldc, float scale) {
    __shared__ f16x8 lsA[4][128];  // [k-block][row] : 8 KB
    __shared__ f16x8 lsB[4][128];

    const int tid = threadIdx.x;
    const int lane = tid & 63;
    const int wave = tid >> 6;
    const int wm = wave >> 1;      // 2x2 wave grid, each wave owns 64x64
    const int wn = wave & 1;
    const int z = blockIdx.z;
    const long m_base = (long)blockIdx.y * 128;
    const long n_base = (long)blockIdx.x * 128;
    const f16* Ab = A + (long)z * sA;
    const f16* Bb = B + (long)z * sB;

    f32x4 acc[4][4];
#pragma unroll
    for (int i = 0; i < 4; ++i)
#pragma unroll
        for (int j = 0; j < 4; ++j) acc[i][j] = (f32x4){0.f, 0.f, 0.f, 0.f};

    for (int k0 = 0; k0 < K; k0 += 32) {
        __syncthreads();
#pragma unroll
        for (int c = 0; c < 2; ++c) {
            int i = tid + c * 256;          // chunk 0..511 (16B each)
            int kb = i >> 7;                // 0..3
            int r = i & 127;                // 0..127
            const f16* ga = Ab + (m_base + r) * (long)lda + k0 + kb * 8;
            GLD_LDS16(ga, &lsA[kb][r]);
            const f16* gb = Bb + (n_base + r) * (long)ldb + k0 + kb * 8;
            GLD_LDS16(gb, &lsB[kb][r]);
        }
        __syncthreads();

        const int kb = lane >> 4;
        const int fr = lane & 15;
        f16x8 af[4], bf[4];
#pragma unroll
        for (int mi = 0; mi < 4; ++mi) af[mi] = lsA[kb][wm * 64 + mi * 16 + fr];
#pragma unroll
        for (int ni = 0; ni < 4; ++ni) bf[ni] = lsB[kb][wn * 64 + ni * 16 + fr];
#pragma unroll
        for (int mi = 0; mi < 4; ++mi)
#pragma unroll
            for (int ni = 0; ni < 4; ++ni)
                acc[mi][ni] = __builtin_amdgcn_mfma_f32_16x16x32_f16(
                    af[mi], bf[ni], acc[mi][ni], 0, 0, 0);
    }

    // epilogue: C/D layout col = lane&15, row = (lane>>4)*4 + j
    const int fr = lane & 15;
    const int rq = lane >> 4;
#pragma unroll
    for (int mi = 0; mi < 4; ++mi) {
        long r0 = m_base + wm * 64 + mi * 16 + rq * 4;
#pragma unroll
        for (int ni = 0; ni < 4; ++ni) {
            long c = n_base + wn * 64 + ni * 16 + fr;
            if constexpr (MODE == 0) {
                f16* C = (f16*)Cv + (long)z * sC;
#pragma unroll
                for (int j = 0; j < 4; ++j)
                    C[(r0 + j) * (long)ldc + c] = (f16)(acc[mi][ni][j] * scale);
            } else if constexpr (MODE == 1) {
                f16* C = (f16*)Cv;
                long b = r0 >> 11;
                long s = r0 & 2047;
                f16x4 v;
#pragma unroll
                for (int j = 0; j < 4; ++j) v[j] = (f16)(acc[mi][ni][j] * scale);
                *(f16x4*)&C[(b << 21) + c * 2048 + s] = v;
            } else {
                float* C = (float*)Cv + (long)z * sC;
#pragma unroll
                for (int j = 0; j < 4; ++j)
                    C[(r0 + j) * (long)ldc + c] = acc[mi][ni][j] * scale;
            }
        }
    }
}

// ---------------------------------------------------------------------------
// in-place row softmax on fp16 [nrows][2048]
__global__ __launch_bounds__(256) void softmax_inplace(f16* __restrict__ S) {
    f16* p = S + (long)blockIdx.x * 2048;
    const int t = threadIdx.x;
    const int lane = t & 63;
    const int wv = t >> 6;
    __shared__ float red[8];

    f16x8 v = *(f16x8*)&p[t * 8];
    float f[8];
#pragma unroll
    for (int e = 0; e < 8; ++e) f[e] = (float)v[e];

    float m = -1e30f;
#pragma unroll
    for (int e = 0; e < 8; ++e) m = fmaxf(m, f[e]);
#pragma unroll
    for (int o = 32; o; o >>= 1) m = fmaxf(m, __shfl_xor(m, o));
    if (lane == 0) red[wv] = m;
    __syncthreads();
    m = fmaxf(fmaxf(red[0], red[1]), fmaxf(red[2], red[3]));

    float e8[8];
    float sum = 0.f;
#pragma unroll
    for (int e = 0; e < 8; ++e) {
        e8[e] = __expf(f[e] - m);
        sum += e8[e];
    }
#pragma unroll
    for (int o = 32; o; o >>= 1) sum += __shfl_xor(sum, o);
    if (lane == 0) red[4 + wv] = sum;
    __syncthreads();
    sum = red[4] + red[5] + red[6] + red[7];

    float inv = 1.f / sum;
    f16x8 ov;
#pragma unroll
    for (int e = 0; e < 8; ++e) ov[e] = (f16)(e8[e] * inv);
    *(f16x8*)&p[t * 8] = ov;
}

// ---------------------------------------------------------------------------
extern "C" void kernel_launch(void* const* d_in, const int* in_sizes, int n_in,
                              void* d_out, int out_size, void* d_ws, size_t ws_size,
                              hipStream_t stream) {
    const float* x = (const float*)d_in[0];    // [8,2048,1024]
    const float* w = (const float*)d_in[1];    // [3,1024,1024]
    float* out = (float*)d_out;                // [8,2048,1024] f32
    char* ws = (char*)d_ws;

    // workspace layout (bytes); sp overlaps dead xh/wh regions -> 160 MiB total
    f16* qh = (f16*)(ws + 0);            // 32 MB  [8*2048][1024]
    f16* kh = (f16*)(ws + 33554432);     // 32 MB
    f16* vt = (f16*)(ws + 67108864);     // 32 MB  [8][1024][2048] (V^T)
    f16* xh = (f16*)(ws + 100663296);    // 32 MB  (dead after QKV gemms)
    f16* wh = (f16*)(ws + 134217728);    // 6 MB   W^T fp16 (dead after QKV gemms)
    f16* sp = (f16*)(ws + 100663296);    // 64 MB  scores/P [8][2048][2048]

    // 1) casts
    cast_x_kernel<<<8192, 256, 0, stream>>>(x, xh);
    cast_transpose_w<<<dim3(16, 16, 3), 256, 0, stream>>>(w, wh);

    // 2) Q,K projections: C[z] = xh * WT[z]^T, z=0(Q),1(K)
    gemm_bt<0><<<dim3(8, 128, 2), 256, 0, stream>>>(
        xh, wh, qh, 1024, 1024, 1024, 0L, 1048576L, 16777216L, 1024, 1.0f);
    // 2b) V projection stored transposed per batch
    gemm_bt<1><<<dim3(8, 128, 1), 256, 0, stream>>>(
        xh, wh + 2097152, vt, 1024, 1024, 1024, 0L, 0L, 0L, 0, 1.0f);

    // 3) scores = Q * K^T * 0.125 -> sp fp16 (per batch)
    gemm_bt<0><<<dim3(16, 16, 8), 256, 0, stream>>>(
        qh, kh, sp, 1024, 1024, 1024, 2097152L, 2097152L, 4194304L, 2048, 0.125f);

    // 4) softmax rows in place (8*2048 rows)
    softmax_inplace<<<16384, 256, 0, stream>>>(sp);

    // 5) out = P * V  (B operand = V^T rows, f32 output)
    gemm_bt<2><<<dim3(8, 16, 8), 256, 0, stream>>>(
        sp, vt, out, 2048, 2048, 2048, 4194304L, 2097152L, 2097152L, 1024, 1.0f);
}

// Round 2
// 544.218 us; speedup vs baseline: 1.1850x; 1.1850x over previous
//
#include <hip/hip_runtime.h>

typedef _Float16 f16;
typedef f16 f16x8 __attribute__((ext_vector_type(8)));
typedef f16 f16x4 __attribute__((ext_vector_type(4)));
typedef float f32x4 __attribute__((ext_vector_type(4)));

#define GLD_LDS16(g, l) __builtin_amdgcn_global_load_lds( \
    (const __attribute__((address_space(1))) void*)(g),   \
    (__attribute__((address_space(3))) void*)(l), 16, 0, 0)

__device__ __forceinline__ void bar() {
    asm volatile("" ::: "memory");
    __builtin_amdgcn_s_barrier();
    asm volatile("" ::: "memory");
}
__device__ __forceinline__ void wait_vm0() {
    asm volatile("s_waitcnt vmcnt(0)" ::: "memory");
}

// ---------------------------------------------------------------------------
// cast x (f32) -> fp16, contiguous
__global__ __launch_bounds__(256) void cast_x_kernel(const float* __restrict__ x,
                                                     f16* __restrict__ xh) {
    long i = ((long)blockIdx.x * 256 + threadIdx.x) * 8;
    float4 a = *(const float4*)&x[i];
    float4 b = *(const float4*)&x[i + 4];
    f16x8 v;
    v[0] = (f16)a.x; v[1] = (f16)a.y; v[2] = (f16)a.z; v[3] = (f16)a.w;
    v[4] = (f16)b.x; v[5] = (f16)b.y; v[6] = (f16)b.z; v[7] = (f16)b.w;
    *(f16x8*)&xh[i] = v;
}

// cast + transpose weights: W[i][d][o] f32 -> WT[i][o][d] fp16 (64x64 tiles)
__global__ __launch_bounds__(256) void cast_transpose_w(const float* __restrict__ W,
                                                        f16* __restrict__ WT) {
    __shared__ float tile[64][65];
    const int iz = blockIdx.z;
    const int d0 = blockIdx.y * 64;
    const int o0 = blockIdx.x * 64;
    const float* Wi = W + (long)iz * 1024 * 1024;
    f16* WTi = WT + (long)iz * 1024 * 1024;
    const int t = threadIdx.x;
#pragma unroll
    for (int j = 0; j < 4; ++j) {
        int idx = t + j * 256;          // 1024 float4 chunks
        int r = idx >> 4;               // 0..63 (d)
        int c4 = (idx & 15) * 4;        // 0..60 (o)
        float4 v = *(const float4*)&Wi[(long)(d0 + r) * 1024 + o0 + c4];
        tile[r][c4 + 0] = v.x; tile[r][c4 + 1] = v.y;
        tile[r][c4 + 2] = v.z; tile[r][c4 + 3] = v.w;
    }
    __syncthreads();
#pragma unroll
    for (int j = 0; j < 2; ++j) {
        int idx = t + j * 256;          // 512 chunks of 8 halfs
        int ol = idx >> 3;              // 0..63 (o)
        int c8 = (idx & 7) * 8;         // 0..56 (d)
        f16x8 v;
#pragma unroll
        for (int e = 0; e < 8; ++e) v[e] = (f16)tile[c8 + e][ol];
        *(f16x8*)&WTi[(long)(o0 + ol) * 1024 + d0 + c8] = v;
    }
}

// ---------------------------------------------------------------------------
// 128x128 tile gemm_bt, 2-phase software-pipelined double-buffer (T3-minimum):
// C = A * B^T, A[m][k], B[n][k] row-major.
// MODE 0: C fp16 row-major (C + z*sC, stride ldc), scaled
// MODE 2: C f32 row-major
// MODE 3: fused QKV epilogue: cols [0,1024) -> Q rows, [1024,2048) -> K rows,
//         [2048,3072) -> V stored transposed [b][o][s]. Cv = ws base.
template <int MODE>
__global__ __launch_bounds__(256, 4)
void gemm_bt(const f16* __restrict__ A, const f16* __restrict__ B,
             void* __restrict__ Cv,
             int lda, int ldb, int K,
             long sA, long sB, long sC, int ldc, float scale) {
    // [buf][A=0/B=1][kb][row] : 32 KB total
    __shared__ f16x8 ls[2][2][4][128];

    const int tid = threadIdx.x;
    const int lane = tid & 63;
    const int wave = tid >> 6;
    const int wm = wave >> 1;      // 2x2 wave grid, each wave owns 64x64
    const int wn = wave & 1;
    const int z = blockIdx.z;
    const long m_base = (long)blockIdx.y * 128;
    const long n_base = (long)blockIdx.x * 128;
    const f16* Ab = A + (long)z * sA;
    const f16* Bb = B + (long)z * sB;

    // staging geometry: 512 16B chunks per matrix, 2 per thread per matrix
    const int i0 = tid;
    const int i1 = tid + 256;
    const int kbA0 = i0 >> 7, rA0 = i0 & 127;
    const int kbA1 = i1 >> 7, rA1 = i1 & 127;
    const f16* gA0 = Ab + (m_base + rA0) * (long)lda + kbA0 * 8;
    const f16* gA1 = Ab + (m_base + rA1) * (long)lda + kbA1 * 8;
    const f16* gB0 = Bb + (n_base + rA0) * (long)ldb + kbA0 * 8;
    const f16* gB1 = Bb + (n_base + rA1) * (long)ldb + kbA1 * 8;

    auto stage = [&](int buf, int k0) {
        GLD_LDS16(gA0 + k0, &ls[buf][0][kbA0][rA0]);
        GLD_LDS16(gA1 + k0, &ls[buf][0][kbA1][rA1]);
        GLD_LDS16(gB0 + k0, &ls[buf][1][kbA0][rA0]);
        GLD_LDS16(gB1 + k0, &ls[buf][1][kbA1][rA1]);
    };

    f32x4 acc[4][4];
#pragma unroll
    for (int i = 0; i < 4; ++i)
#pragma unroll
        for (int j = 0; j < 4; ++j) acc[i][j] = (f32x4){0.f, 0.f, 0.f, 0.f};

    const int NT = K >> 5;
    stage(0, 0);
    wait_vm0();
    bar();

    int cur = 0;
    const int kb = lane >> 4;
    const int fr = lane & 15;
    for (int t = 0; t < NT; ++t) {
        if (t + 1 < NT) stage(cur ^ 1, (t + 1) << 5);   // issue next-tile loads FIRST

        f16x8 af[4], bf[4];
#pragma unroll
        for (int mi = 0; mi < 4; ++mi) af[mi] = ls[cur][0][kb][wm * 64 + mi * 16 + fr];
#pragma unroll
        for (int ni = 0; ni < 4; ++ni) bf[ni] = ls[cur][1][kb][wn * 64 + ni * 16 + fr];
#pragma unroll
        for (int mi = 0; mi < 4; ++mi)
#pragma unroll
            for (int ni = 0; ni < 4; ++ni)
                acc[mi][ni] = __builtin_amdgcn_mfma_f32_16x16x32_f16(
                    af[mi], bf[ni], acc[mi][ni], 0, 0, 0);

        wait_vm0();    // own-wave prefetch done (overlapped with ds_read+MFMA above)
        bar();         // all waves: buf[cur^1] staged, buf[cur] reads retired
        cur ^= 1;
    }

    // epilogue: C/D layout col = lane&15, row = (lane>>4)*4 + j
    const int rq = lane >> 4;
#pragma unroll
    for (int mi = 0; mi < 4; ++mi) {
        long r0 = m_base + wm * 64 + mi * 16 + rq * 4;
#pragma unroll
        for (int ni = 0; ni < 4; ++ni) {
            long c = n_base + wn * 64 + ni * 16 + fr;
            if constexpr (MODE == 0) {
                f16* C = (f16*)Cv + (long)z * sC;
#pragma unroll
                for (int j = 0; j < 4; ++j)
                    C[(r0 + j) * (long)ldc + c] = (f16)(acc[mi][ni][j] * scale);
            } else if constexpr (MODE == 2) {
                float* C = (float*)Cv + (long)z * sC;
#pragma unroll
                for (int j = 0; j < 4; ++j)
                    C[(r0 + j) * (long)ldc + c] = acc[mi][ni][j] * scale;
            } else {  // MODE 3: fused QKV
                f16* W = (f16*)Cv;
                if (c < 2048) {
                    // Q at elem 0, K at elem 16777216, both [16384][1024]
                    f16* C = W + (c >> 10) * 16777216L + (c & 1023);
#pragma unroll
                    for (int j = 0; j < 4; ++j)
                        C[(r0 + j) * 1024L] = (f16)acc[mi][ni][j];
                } else {
                    // V^T at elem 33554432: [8][1024][2048]
                    long o = c - 2048;
                    long b = r0 >> 11;
                    long s = r0 & 2047;
                    f16x4 v;
#pragma unroll
                    for (int j = 0; j < 4; ++j) v[j] = (f16)acc[mi][ni][j];
                    *(f16x4*)&W[33554432L + b * 2097152L + o * 2048L + s] = v;
                }
            }
        }
    }
}

// ---------------------------------------------------------------------------
// in-place row softmax on fp16 [nrows][2048]
__global__ __launch_bounds__(256) void softmax_inplace(f16* __restrict__ S) {
    f16* p = S + (long)blockIdx.x * 2048;
    const int t = threadIdx.x;
    const int lane = t & 63;
    const int wv = t >> 6;
    __shared__ float red[8];

    f16x8 v = *(f16x8*)&p[t * 8];
    float f[8];
#pragma unroll
    for (int e = 0; e < 8; ++e) f[e] = (float)v[e];

    float m = -1e30f;
#pragma unroll
    for (int e = 0; e < 8; ++e) m = fmaxf(m, f[e]);
#pragma unroll
    for (int o = 32; o; o >>= 1) m = fmaxf(m, __shfl_xor(m, o));
    if (lane == 0) red[wv] = m;
    __syncthreads();
    m = fmaxf(fmaxf(red[0], red[1]), fmaxf(red[2], red[3]));

    float e8[8];
    float sum = 0.f;
#pragma unroll
    for (int e = 0; e < 8; ++e) {
        e8[e] = __expf(f[e] - m);
        sum += e8[e];
    }
#pragma unroll
    for (int o = 32; o; o >>= 1) sum += __shfl_xor(sum, o);
    if (lane == 0) red[4 + wv] = sum;
    __syncthreads();
    sum = red[4] + red[5] + red[6] + red[7];

    float inv = 1.f / sum;
    f16x8 ov;
#pragma unroll
    for (int e = 0; e < 8; ++e) ov[e] = (f16)(e8[e] * inv);
    *(f16x8*)&p[t * 8] = ov;
}

// ---------------------------------------------------------------------------
extern "C" void kernel_launch(void* const* d_in, const int* in_sizes, int n_in,
                              void* d_out, int out_size, void* d_ws, size_t ws_size,
                              hipStream_t stream) {
    const float* x = (const float*)d_in[0];    // [8,2048,1024]
    const float* w = (const float*)d_in[1];    // [3,1024,1024]
    float* out = (float*)d_out;                // [8,2048,1024] f32
    char* ws = (char*)d_ws;

    // workspace layout (bytes); sp overlaps dead xh/wh regions -> 160 MiB total
    f16* qh = (f16*)(ws + 0);            // 32 MB  [8*2048][1024]  (Q)
    f16* kh = (f16*)(ws + 33554432);     // 32 MB  (K)
    f16* vt = (f16*)(ws + 67108864);     // 32 MB  [8][1024][2048] (V^T)
    f16* xh = (f16*)(ws + 100663296);    // 32 MB  (dead after QKV gemm)
    f16* wh = (f16*)(ws + 134217728);    // 6 MB   W^T fp16 [3072][1024] (dead after QKV)
    f16* sp = (f16*)(ws + 100663296);    // 64 MB  scores/P [8][2048][2048]

    // 1) casts
    cast_x_kernel<<<8192, 256, 0, stream>>>(x, xh);
    cast_transpose_w<<<dim3(16, 16, 3), 256, 0, stream>>>(w, wh);

    // 2) fused QKV projection: [16384][1024] x [3072][1024]^T, epilogue splits Q/K/V^T
    gemm_bt<3><<<dim3(24, 128, 1), 256, 0, stream>>>(
        xh, wh, ws, 1024, 1024, 1024, 0L, 0L, 0L, 0, 1.0f);

    // 3) scores = Q * K^T * 0.125 -> sp fp16 (per batch)
    gemm_bt<0><<<dim3(16, 16, 8), 256, 0, stream>>>(
        qh, kh, sp, 1024, 1024, 1024, 2097152L, 2097152L, 4194304L, 2048, 0.125f);

    // 4) softmax rows in place (8*2048 rows)
    softmax_inplace<<<16384, 256, 0, stream>>>(sp);

    // 5) out = P * V  (B operand = V^T rows, f32 output)
    gemm_bt<2><<<dim3(8, 16, 8), 256, 0, stream>>>(
        sp, vt, out, 2048, 2048, 2048, 4194304L, 2097152L, 2097152L, 1024, 1.0f);
}

// Round 3
// 535.310 us; speedup vs baseline: 1.2048x; 1.0166x over previous
//
#include <hip/hip_runtime.h>

typedef _Float16 f16;
typedef f16 f16x8 __attribute__((ext_vector_type(8)));
typedef f16 f16x4 __attribute__((ext_vector_type(4)));
typedef float f32x4 __attribute__((ext_vector_type(4)));

#define GLD_LDS16(g, l) __builtin_amdgcn_global_load_lds( \
    (const __attribute__((address_space(1))) void*)(g),   \
    (__attribute__((address_space(3))) void*)(l), 16, 0, 0)

__device__ __forceinline__ void bar() {
    asm volatile("" ::: "memory");
    __builtin_amdgcn_s_barrier();
    asm volatile("" ::: "memory");
}
#define WAIT_VM(n) asm volatile("s_waitcnt vmcnt(" #n ")" ::: "memory")

// ---------------------------------------------------------------------------
// cast x (f32) -> fp16, contiguous
__global__ __launch_bounds__(256) void cast_x_kernel(const float* __restrict__ x,
                                                     f16* __restrict__ xh) {
    long i = ((long)blockIdx.x * 256 + threadIdx.x) * 8;
    float4 a = *(const float4*)&x[i];
    float4 b = *(const float4*)&x[i + 4];
    f16x8 v;
    v[0] = (f16)a.x; v[1] = (f16)a.y; v[2] = (f16)a.z; v[3] = (f16)a.w;
    v[4] = (f16)b.x; v[5] = (f16)b.y; v[6] = (f16)b.z; v[7] = (f16)b.w;
    *(f16x8*)&xh[i] = v;
}

// cast + transpose weights: W[i][d][o] f32 -> WT[i][o][d] fp16 (64x64 tiles)
__global__ __launch_bounds__(256) void cast_transpose_w(const float* __restrict__ W,
                                                        f16* __restrict__ WT) {
    __shared__ float tile[64][65];
    const int iz = blockIdx.z;
    const int d0 = blockIdx.y * 64;
    const int o0 = blockIdx.x * 64;
    const float* Wi = W + (long)iz * 1024 * 1024;
    f16* WTi = WT + (long)iz * 1024 * 1024;
    const int t = threadIdx.x;
#pragma unroll
    for (int j = 0; j < 4; ++j) {
        int idx = t + j * 256;          // 1024 float4 chunks
        int r = idx >> 4;               // 0..63 (d)
        int c4 = (idx & 15) * 4;        // 0..60 (o)
        float4 v = *(const float4*)&Wi[(long)(d0 + r) * 1024 + o0 + c4];
        tile[r][c4 + 0] = v.x; tile[r][c4 + 1] = v.y;
        tile[r][c4 + 2] = v.z; tile[r][c4 + 3] = v.w;
    }
    __syncthreads();
#pragma unroll
    for (int j = 0; j < 2; ++j) {
        int idx = t + j * 256;          // 512 chunks of 8 halfs
        int ol = idx >> 3;              // 0..63 (o)
        int c8 = (idx & 7) * 8;         // 0..56 (d)
        f16x8 v;
#pragma unroll
        for (int e = 0; e < 8; ++e) v[e] = (f16)tile[c8 + e][ol];
        *(f16x8*)&WTi[(long)(o0 + ol) * 1024 + d0 + c8] = v;
    }
}

// ---------------------------------------------------------------------------
// 128x128 tile gemm_bt, 3-buffer distance-2 pipeline (T3+T4, counted vmcnt):
// C = A * B^T, A[m][k], B[n][k] row-major.
// Per K-step: vmcnt(4) [tile-t loads done, tile-t+1 still in flight] -> barrier
// -> issue tile-t+2 stage into buf[(t-1)%3] -> ds_read+MFMA buf[t%3].
// Safety at the barrier: each wave drained its own tile-t loads (vmcnt first)
// and consumed its buf[t-1] ds_reads (MFMA lgkm-waits precede in program
// order), so overwriting buf[(t+2)%3]==buf[(t-1)%3] after it is race-free.
// MODE 0: C fp16 row-major (C + z*sC, stride ldc), scaled
// MODE 2: C f32 row-major
// MODE 3: fused QKV epilogue: cols [0,1024) -> Q rows, [1024,2048) -> K rows,
//         [2048,3072) -> V stored transposed [b][o][s]. Cv = ws base.
template <int MODE>
__global__ __launch_bounds__(256, 3)
void gemm_bt(const f16* __restrict__ A, const f16* __restrict__ B,
             void* __restrict__ Cv,
             int lda, int ldb, int K,
             long sA, long sB, long sC, int ldc, float scale) {
    // [buf][A=0/B=1][kb][row] : 3 x 16 KB = 48 KB -> 3 blocks/CU
    __shared__ f16x8 ls[3][2][4][128];

    const int tid = threadIdx.x;
    const int lane = tid & 63;
    const int wave = tid >> 6;
    const int wm = wave >> 1;      // 2x2 wave grid, each wave owns 64x64
    const int wn = wave & 1;
    const int z = blockIdx.z;
    const long m_base = (long)blockIdx.y * 128;
    const long n_base = (long)blockIdx.x * 128;
    const f16* Ab = A + (long)z * sA;
    const f16* Bb = B + (long)z * sB;

    // staging geometry: 512 16B chunks per matrix, 2 per thread per matrix
    const int i0 = tid;
    const int i1 = tid + 256;
    const int kbA0 = i0 >> 7, rA0 = i0 & 127;
    const int kbA1 = i1 >> 7, rA1 = i1 & 127;
    const f16* gA0 = Ab + (m_base + rA0) * (long)lda + kbA0 * 8;
    const f16* gA1 = Ab + (m_base + rA1) * (long)lda + kbA1 * 8;
    const f16* gB0 = Bb + (n_base + rA0) * (long)ldb + kbA0 * 8;
    const f16* gB1 = Bb + (n_base + rA1) * (long)ldb + kbA1 * 8;

    auto stage = [&](int buf, int k0) {
        GLD_LDS16(gA0 + k0, &ls[buf][0][kbA0][rA0]);
        GLD_LDS16(gA1 + k0, &ls[buf][0][kbA1][rA1]);
        GLD_LDS16(gB0 + k0, &ls[buf][1][kbA0][rA0]);
        GLD_LDS16(gB1 + k0, &ls[buf][1][kbA1][rA1]);
    };

    f32x4 acc[4][4];
#pragma unroll
    for (int i = 0; i < 4; ++i)
#pragma unroll
        for (int j = 0; j < 4; ++j) acc[i][j] = (f32x4){0.f, 0.f, 0.f, 0.f};

    const int NT = K >> 5;         // K-steps of 32 (always >= 32 here)
    stage(0, 0);
    stage(1, 32);

    const int kb = lane >> 4;
    const int fr = lane & 15;
    int cur = 0;
    for (int t = 0; t < NT; ++t) {
        if (t + 1 < NT) { WAIT_VM(4); } else { WAIT_VM(0); }
        bar();
        if (t + 2 < NT) stage((cur + 2) % 3, (t + 2) << 5);

        f16x8 af[4], bf[4];
#pragma unroll
        for (int mi = 0; mi < 4; ++mi) af[mi] = ls[cur][0][kb][wm * 64 + mi * 16 + fr];
#pragma unroll
        for (int ni = 0; ni < 4; ++ni) bf[ni] = ls[cur][1][kb][wn * 64 + ni * 16 + fr];
#pragma unroll
        for (int mi = 0; mi < 4; ++mi)
#pragma unroll
            for (int ni = 0; ni < 4; ++ni)
                acc[mi][ni] = __builtin_amdgcn_mfma_f32_16x16x32_f16(
                    af[mi], bf[ni], acc[mi][ni], 0, 0, 0);

        cur = (cur + 1) % 3;
    }

    // epilogue: C/D layout col = lane&15, row = (lane>>4)*4 + j
    const int rq = lane >> 4;
#pragma unroll
    for (int mi = 0; mi < 4; ++mi) {
        long r0 = m_base + wm * 64 + mi * 16 + rq * 4;
#pragma unroll
        for (int ni = 0; ni < 4; ++ni) {
            long c = n_base + wn * 64 + ni * 16 + fr;
            if constexpr (MODE == 0) {
                f16* C = (f16*)Cv + (long)z * sC;
#pragma unroll
                for (int j = 0; j < 4; ++j)
                    C[(r0 + j) * (long)ldc + c] = (f16)(acc[mi][ni][j] * scale);
            } else if constexpr (MODE == 2) {
                float* C = (float*)Cv + (long)z * sC;
#pragma unroll
                for (int j = 0; j < 4; ++j)
                    C[(r0 + j) * (long)ldc + c] = acc[mi][ni][j] * scale;
            } else {  // MODE 3: fused QKV
                f16* W = (f16*)Cv;
                if (c < 2048) {
                    // Q at elem 0, K at elem 16777216, both [16384][1024]
                    f16* C = W + (c >> 10) * 16777216L + (c & 1023);
#pragma unroll
                    for (int j = 0; j < 4; ++j)
                        C[(r0 + j) * 1024L] = (f16)acc[mi][ni][j];
                } else {
                    // V^T at elem 33554432: [8][1024][2048]
                    long o = c - 2048;
                    long b = r0 >> 11;
                    long s = r0 & 2047;
                    f16x4 v;
#pragma unroll
                    for (int j = 0; j < 4; ++j) v[j] = (f16)acc[mi][ni][j];
                    *(f16x4*)&W[33554432L + b * 2097152L + o * 2048L + s] = v;
                }
            }
        }
    }
}

// ---------------------------------------------------------------------------
// in-place row softmax on fp16 [nrows][2048]
__global__ __launch_bounds__(256) void softmax_inplace(f16* __restrict__ S) {
    f16* p = S + (long)blockIdx.x * 2048;
    const int t = threadIdx.x;
    const int lane = t & 63;
    const int wv = t >> 6;
    __shared__ float red[8];

    f16x8 v = *(f16x8*)&p[t * 8];
    float f[8];
#pragma unroll
    for (int e = 0; e < 8; ++e) f[e] = (float)v[e];

    float m = -1e30f;
#pragma unroll
    for (int e = 0; e < 8; ++e) m = fmaxf(m, f[e]);
#pragma unroll
    for (int o = 32; o; o >>= 1) m = fmaxf(m, __shfl_xor(m, o));
    if (lane == 0) red[wv] = m;
    __syncthreads();
    m = fmaxf(fmaxf(red[0], red[1]), fmaxf(red[2], red[3]));

    float e8[8];
    float sum = 0.f;
#pragma unroll
    for (int e = 0; e < 8; ++e) {
        e8[e] = __expf(f[e] - m);
        sum += e8[e];
    }
#pragma unroll
    for (int o = 32; o; o >>= 1) sum += __shfl_xor(sum, o);
    if (lane == 0) red[4 + wv] = sum;
    __syncthreads();
    sum = red[4] + red[5] + red[6] + red[7];

    float inv = 1.f / sum;
    f16x8 ov;
#pragma unroll
    for (int e = 0; e < 8; ++e) ov[e] = (f16)(e8[e] * inv);
    *(f16x8*)&p[t * 8] = ov;
}

// ---------------------------------------------------------------------------
extern "C" void kernel_launch(void* const* d_in, const int* in_sizes, int n_in,
                              void* d_out, int out_size, void* d_ws, size_t ws_size,
                              hipStream_t stream) {
    const float* x = (const float*)d_in[0];    // [8,2048,1024]
    const float* w = (const float*)d_in[1];    // [3,1024,1024]
    float* out = (float*)d_out;                // [8,2048,1024] f32
    char* ws = (char*)d_ws;

    // workspace layout (bytes); sp overlaps dead xh/wh regions -> 160 MiB total
    f16* qh = (f16*)(ws + 0);            // 32 MB  [8*2048][1024]  (Q)
    f16* kh = (f16*)(ws + 33554432);     // 32 MB  (K)
    f16* vt = (f16*)(ws + 67108864);     // 32 MB  [8][1024][2048] (V^T)
    f16* xh = (f16*)(ws + 100663296);    // 32 MB  (dead after QKV gemm)
    f16* wh = (f16*)(ws + 134217728);    // 6 MB   W^T fp16 [3072][1024] (dead after QKV)
    f16* sp = (f16*)(ws + 100663296);    // 64 MB  scores/P [8][2048][2048]

    // 1) casts
    cast_x_kernel<<<8192, 256, 0, stream>>>(x, xh);
    cast_transpose_w<<<dim3(16, 16, 3), 256, 0, stream>>>(w, wh);

    // 2) fused QKV projection: [16384][1024] x [3072][1024]^T, epilogue splits Q/K/V^T
    gemm_bt<3><<<dim3(24, 128, 1), 256, 0, stream>>>(
        xh, wh, ws, 1024, 1024, 1024, 0L, 0L, 0L, 0, 1.0f);

    // 3) scores = Q * K^T * 0.125 -> sp fp16 (per batch)
    gemm_bt<0><<<dim3(16, 16, 8), 256, 0, stream>>>(
        qh, kh, sp, 1024, 1024, 1024, 2097152L, 2097152L, 4194304L, 2048, 0.125f);

    // 4) softmax rows in place (8*2048 rows)
    softmax_inplace<<<16384, 256, 0, stream>>>(sp);

    // 5) out = P * V  (B operand = V^T rows, f32 output)
    gemm_bt<2><<<dim3(8, 16, 8), 256, 0, stream>>>(
        sp, vt, out, 2048, 2048, 2048, 4194304L, 2097152L, 2097152L, 1024, 1.0f);
}

// Round 4
// 317.246 us; speedup vs baseline: 2.0329x; 1.6874x over previous
//
#include <hip/hip_runtime.h>

typedef _Float16 f16;
typedef f16 f16x8 __attribute__((ext_vector_type(8)));
typedef f16 f16x4 __attribute__((ext_vector_type(4)));
typedef float f32x4 __attribute__((ext_vector_type(4)));

#define GLD_LDS16(g, l) __builtin_amdgcn_global_load_lds( \
    (const __attribute__((address_space(1))) void*)(g),   \
    (__attribute__((address_space(3))) void*)(l), 16, 0, 0)

__device__ __forceinline__ void bar() {
    asm volatile("" ::: "memory");
    __builtin_amdgcn_s_barrier();
    asm volatile("" ::: "memory");
}
#define WAIT_VM(n) { asm volatile("s_waitcnt vmcnt(" #n ")" ::: "memory"); \
                     __builtin_amdgcn_sched_barrier(0); }
#define LGKM0()    { asm volatile("s_waitcnt lgkmcnt(0)" ::: "memory"); \
                     __builtin_amdgcn_sched_barrier(0); }

// ---------------------------------------------------------------------------
__global__ __launch_bounds__(256) void cast_x_kernel(const float* __restrict__ x,
                                                     f16* __restrict__ xh) {
    long i = ((long)blockIdx.x * 256 + threadIdx.x) * 8;
    float4 a = *(const float4*)&x[i];
    float4 b = *(const float4*)&x[i + 4];
    f16x8 v;
    v[0] = (f16)a.x; v[1] = (f16)a.y; v[2] = (f16)a.z; v[3] = (f16)a.w;
    v[4] = (f16)b.x; v[5] = (f16)b.y; v[6] = (f16)b.z; v[7] = (f16)b.w;
    *(f16x8*)&xh[i] = v;
}

// cast + transpose weights: W[i][d][o] f32 -> WT[i][o][d] fp16 (64x64 tiles)
__global__ __launch_bounds__(256) void cast_transpose_w(const float* __restrict__ W,
                                                        f16* __restrict__ WT) {
    __shared__ float tile[64][65];
    const int iz = blockIdx.z;
    const int d0 = blockIdx.y * 64;
    const int o0 = blockIdx.x * 64;
    const float* Wi = W + (long)iz * 1024 * 1024;
    f16* WTi = WT + (long)iz * 1024 * 1024;
    const int t = threadIdx.x;
#pragma unroll
    for (int j = 0; j < 4; ++j) {
        int idx = t + j * 256;
        int r = idx >> 4;
        int c4 = (idx & 15) * 4;
        float4 v = *(const float4*)&Wi[(long)(d0 + r) * 1024 + o0 + c4];
        tile[r][c4 + 0] = v.x; tile[r][c4 + 1] = v.y;
        tile[r][c4 + 2] = v.z; tile[r][c4 + 3] = v.w;
    }
    __syncthreads();
#pragma unroll
    for (int j = 0; j < 2; ++j) {
        int idx = t + j * 256;
        int ol = idx >> 3;
        int c8 = (idx & 7) * 8;
        f16x8 v;
#pragma unroll
        for (int e = 0; e < 8; ++e) v[e] = (f16)tile[c8 + e][ol];
        *(f16x8*)&WTi[(long)(o0 + ol) * 1024 + d0 + c8] = v;
    }
}

// ---------------------------------------------------------------------------
// 256x256 tile, BK=64, 8-phase schedule (T2+T3+T4+T5), 512 threads = 8 waves
// (2 m-waves x 4 n-waves), per-wave output 128x64, LDS 128 KiB ring of 8
// half-tile slots (per buffer: A0,A1,B0,B1 of 16 KB each).
//
// Per K-tile group j (4 phases):
//   ph1: ds_read all B-frags(8) + A-frags mi0-3(8); stage K(j+1).A1;
//        bar; lgkmcnt(0); setprio1; 16 MFMA (m0 x n01); setprio0; bar
//   ph2: stage K(j+2).B0; bar; 16 MFMA (m0 x n23); bar
//   ph3: ds_read A-frags mi4-7(8); stage K(j+2).B1; bar; lgkmcnt(0);
//        16 MFMA (m1 x n01); bar
//   ph4: stage K(j+2).A0; vmcnt(6); bar; 16 MFMA (m1 x n23); bar
// Slot-overwrite safety: B-slots last read ph1, overwritten ph2/ph3;
// A0 last read ph3, overwritten ph4; A1 last read ph3, overwritten next ph1.
// vmcnt(6) at ph4 => everything older than the newest 3 half-tiles landed
// => K(j+1) fully resident before group j+1 reads it.
//
// LDS swizzle (T2, both-sides): read byte ^= ((row&7)<<4); stage keeps dest
// linear and pre-applies the inverse to the global source column.
//
// MODE 0: C fp16 row-major (C + z*sC, stride ldc), scaled
// MODE 2: C f32 row-major
// MODE 3: fused QKV epilogue: cols [0,1024)->Q, [1024,2048)->K,
//         [2048,3072)->V^T [b][o][s]. Cv = ws base.
template <int MODE>
__global__ __launch_bounds__(512, 2)
void gemm256(const f16* __restrict__ A, const f16* __restrict__ B,
             void* __restrict__ Cv, int lda, int ldb, int K,
             long sA, long sB, long sC, int ldc, float scale) {
    extern __shared__ __align__(16) char smem[];
    const int tid = threadIdx.x;
    const int lane = tid & 63;
    const int wave = tid >> 6;
    const int wm = wave >> 2;          // 0..1
    const int wn = wave & 3;           // 0..3
    const int z = blockIdx.z;
    const long m_base = (long)blockIdx.y * 256;
    const long n_base = (long)blockIdx.x * 256;
    const f16* Ab = A + (long)z * sA;
    const f16* Bb = B + (long)z * sB;

    // ---- staging geometry: 1024 chunks of 16B per half-tile, 2 per thread
    const int c_r0 = tid >> 3;                             // rows 0..63 (li=0)
    const int c_col = ((tid & 7) * 8) ^ ((c_r0 & 7) << 3); // inverse-swizzled col
    const long oA0 = (m_base + c_r0) * (long)lda + c_col;
    const long oA1 = oA0 + 64L * lda;                      // li=1: rows 64..127
    const long oB0 = (n_base + c_r0) * (long)ldb + c_col;
    const long oB1 = oB0 + 64L * ldb;

#define ST_A0(bf_, kt_) { long k0_ = (long)(kt_) * 64; \
    char* d_ = smem + (bf_) * 65536 + tid * 16; \
    GLD_LDS16(Ab + oA0 + k0_, d_); GLD_LDS16(Ab + oA1 + k0_, d_ + 8192); }
#define ST_A1(bf_, kt_) { long k0_ = (long)(kt_) * 64 + 128L * lda; \
    char* d_ = smem + (bf_) * 65536 + 16384 + tid * 16; \
    GLD_LDS16(Ab + oA0 + k0_, d_); GLD_LDS16(Ab + oA1 + k0_, d_ + 8192); }
#define ST_B0(bf_, kt_) { long k0_ = (long)(kt_) * 64; \
    char* d_ = smem + (bf_) * 65536 + 32768 + tid * 16; \
    GLD_LDS16(Bb + oB0 + k0_, d_); GLD_LDS16(Bb + oB1 + k0_, d_ + 8192); }
#define ST_B1(bf_, kt_) { long k0_ = (long)(kt_) * 64 + 128L * ldb; \
    char* d_ = smem + (bf_) * 65536 + 49152 + tid * 16; \
    GLD_LDS16(Bb + oB0 + k0_, d_); GLD_LDS16(Bb + oB1 + k0_, d_ + 8192); }

    // ---- fragment read offsets (swizzled)
    const int fr = lane & 15;
    const int rq = lane >> 4;
    const int cs0 = (rq * 16) ^ ((lane & 7) << 4);
    const int cs1 = cs0 ^ 64;
    const int aoff = wm * 16384 + fr * 128;
    const int boff = 32768 + (wn >> 1) * 16384 + (wn & 1) * 8192 + fr * 128;

    f32x4 acc[8][4];
#pragma unroll
    for (int i = 0; i < 8; ++i)
#pragma unroll
        for (int j = 0; j < 4; ++j) acc[i][j] = (f32x4){0.f, 0.f, 0.f, 0.f};

    const int NT = K >> 6;   // K-tiles of 64 (NT >= 2 for all our shapes)

    // ---- prologue: K0 all 4 halves, then K1 B0,B1,A0
    ST_B0(0, 0); ST_B1(0, 0); ST_A0(0, 0); ST_A1(0, 0);
    WAIT_VM(4);
    ST_B0(1, 1); ST_B1(1, 1); ST_A0(1, 1);
    WAIT_VM(6);
    bar();

    for (int j = 0; j < NT; ++j) {
        char* bufb = smem + (j & 1) * 65536;
        const char* Ap = bufb + aoff;
        const char* Bp = bufb + boff;
        f16x8 af[4][2], bf[4][2];

        // ---------- phase 1
#pragma unroll
        for (int ni = 0; ni < 4; ++ni) {
            bf[ni][0] = *(const f16x8*)(Bp + ni * 2048 + cs0);
            bf[ni][1] = *(const f16x8*)(Bp + ni * 2048 + cs1);
        }
#pragma unroll
        for (int i = 0; i < 4; ++i) {
            af[i][0] = *(const f16x8*)(Ap + i * 2048 + cs0);
            af[i][1] = *(const f16x8*)(Ap + i * 2048 + cs1);
        }
        if (j + 1 < NT) ST_A1((j + 1) & 1, j + 1);
        bar();
        LGKM0();
        __builtin_amdgcn_s_setprio(1);
#pragma unroll
        for (int ks = 0; ks < 2; ++ks)
#pragma unroll
            for (int i = 0; i < 4; ++i)
#pragma unroll
                for (int n = 0; n < 2; ++n)
                    acc[i][n] = __builtin_amdgcn_mfma_f32_16x16x32_f16(
                        af[i][ks], bf[n][ks], acc[i][n], 0, 0, 0);
        __builtin_amdgcn_s_setprio(0);
        bar();

        // ---------- phase 2
        if (j + 2 < NT) ST_B0(j & 1, j + 2);
        bar();
        __builtin_amdgcn_s_setprio(1);
#pragma unroll
        for (int ks = 0; ks < 2; ++ks)
#pragma unroll
            for (int i = 0; i < 4; ++i)
#pragma unroll
                for (int n = 0; n < 2; ++n)
                    acc[i][2 + n] = __builtin_amdgcn_mfma_f32_16x16x32_f16(
                        af[i][ks], bf[2 + n][ks], acc[i][2 + n], 0, 0, 0);
        __builtin_amdgcn_s_setprio(0);
        bar();

        // ---------- phase 3
#pragma unroll
        for (int i = 0; i < 4; ++i) {
            af[i][0] = *(const f16x8*)(Ap + (4 + i) * 2048 + cs0);
            af[i][1] = *(const f16x8*)(Ap + (4 + i) * 2048 + cs1);
        }
        if (j + 2 < NT) ST_B1(j & 1, j + 2);
        bar();
        LGKM0();
        __builtin_amdgcn_s_setprio(1);
#pragma unroll
        for (int ks = 0; ks < 2; ++ks)
#pragma unroll
            for (int i = 0; i < 4; ++i)
#pragma unroll
                for (int n = 0; n < 2; ++n)
                    acc[4 + i][n] = __builtin_amdgcn_mfma_f32_16x16x32_f16(
                        af[i][ks], bf[n][ks], acc[4 + i][n], 0, 0, 0);
        __builtin_amdgcn_s_setprio(0);
        bar();

        // ---------- phase 4
        if (j + 2 < NT) {
            ST_A0(j & 1, j + 2);
            WAIT_VM(6);
        } else if (j + 1 < NT) {
            WAIT_VM(0);
        }
        bar();
        __builtin_amdgcn_s_setprio(1);
#pragma unroll
        for (int ks = 0; ks < 2; ++ks)
#pragma unroll
            for (int i = 0; i < 4; ++i)
#pragma unroll
                for (int n = 0; n < 2; ++n)
                    acc[4 + i][2 + n] = __builtin_amdgcn_mfma_f32_16x16x32_f16(
                        af[i][ks], bf[2 + n][ks], acc[4 + i][2 + n], 0, 0, 0);
        __builtin_amdgcn_s_setprio(0);
        bar();
    }

    // ---- epilogue: C/D layout col = lane&15, row = (lane>>4)*4 + j
#pragma unroll
    for (int mi = 0; mi < 8; ++mi) {
        long r0 = m_base + wm * 128 + mi * 16 + rq * 4;
#pragma unroll
        for (int ni = 0; ni < 4; ++ni) {
            long c = n_base + wn * 64 + ni * 16 + fr;
            if constexpr (MODE == 0) {
                f16* C = (f16*)Cv + (long)z * sC;
#pragma unroll
                for (int jj = 0; jj < 4; ++jj)
                    C[(r0 + jj) * (long)ldc + c] = (f16)(acc[mi][ni][jj] * scale);
            } else if constexpr (MODE == 2) {
                float* C = (float*)Cv + (long)z * sC;
#pragma unroll
                for (int jj = 0; jj < 4; ++jj)
                    C[(r0 + jj) * (long)ldc + c] = acc[mi][ni][jj] * scale;
            } else {  // MODE 3: fused QKV
                f16* W = (f16*)Cv;
                if (c < 2048) {
                    f16* C = W + (c >> 10) * 16777216L + (c & 1023);
#pragma unroll
                    for (int jj = 0; jj < 4; ++jj)
                        C[(r0 + jj) * 1024L] = (f16)acc[mi][ni][jj];
                } else {
                    long o = c - 2048;
                    long b = r0 >> 11;
                    long s = r0 & 2047;
                    f16x4 v;
#pragma unroll
                    for (int jj = 0; jj < 4; ++jj) v[jj] = (f16)acc[mi][ni][jj];
                    *(f16x4*)&W[33554432L + b * 2097152L + o * 2048L + s] = v;
                }
            }
        }
    }
#undef ST_A0
#undef ST_A1
#undef ST_B0
#undef ST_B1
}

// ---------------------------------------------------------------------------
// in-place row softmax on fp16 [nrows][2048]
__global__ __launch_bounds__(256) void softmax_inplace(f16* __restrict__ S) {
    f16* p = S + (long)blockIdx.x * 2048;
    const int t = threadIdx.x;
    const int lane = t & 63;
    const int wv = t >> 6;
    __shared__ float red[8];

    f16x8 v = *(f16x8*)&p[t * 8];
    float f[8];
#pragma unroll
    for (int e = 0; e < 8; ++e) f[e] = (float)v[e];

    float m = -1e30f;
#pragma unroll
    for (int e = 0; e < 8; ++e) m = fmaxf(m, f[e]);
#pragma unroll
    for (int o = 32; o; o >>= 1) m = fmaxf(m, __shfl_xor(m, o));
    if (lane == 0) red[wv] = m;
    __syncthreads();
    m = fmaxf(fmaxf(red[0], red[1]), fmaxf(red[2], red[3]));

    float e8[8];
    float sum = 0.f;
#pragma unroll
    for (int e = 0; e < 8; ++e) {
        e8[e] = __expf(f[e] - m);
        sum += e8[e];
    }
#pragma unroll
    for (int o = 32; o; o >>= 1) sum += __shfl_xor(sum, o);
    if (lane == 0) red[4 + wv] = sum;
    __syncthreads();
    sum = red[4] + red[5] + red[6] + red[7];

    float inv = 1.f / sum;
    f16x8 ov;
#pragma unroll
    for (int e = 0; e < 8; ++e) ov[e] = (f16)(e8[e] * inv);
    *(f16x8*)&p[t * 8] = ov;
}

// ---------------------------------------------------------------------------
extern "C" void kernel_launch(void* const* d_in, const int* in_sizes, int n_in,
                              void* d_out, int out_size, void* d_ws, size_t ws_size,
                              hipStream_t stream) {
    const float* x = (const float*)d_in[0];    // [8,2048,1024]
    const float* w = (const float*)d_in[1];    // [3,1024,1024]
    float* out = (float*)d_out;                // [8,2048,1024] f32
    char* ws = (char*)d_ws;

    // workspace layout (bytes); sp overlaps dead xh/wh regions
    f16* qh = (f16*)(ws + 0);            // 32 MB  [8*2048][1024]  (Q)
    f16* kh = (f16*)(ws + 33554432);     // 32 MB  (K)
    f16* vt = (f16*)(ws + 67108864);     // 32 MB  [8][1024][2048] (V^T)
    f16* xh = (f16*)(ws + 100663296);    // 32 MB  (dead after QKV gemm)
    f16* wh = (f16*)(ws + 134217728);    // 6 MB   W^T fp16 [3072][1024]
    f16* sp = (f16*)(ws + 100663296);    // 64 MB  scores/P [8][2048][2048]

    // 1) casts
    cast_x_kernel<<<8192, 256, 0, stream>>>(x, xh);
    cast_transpose_w<<<dim3(16, 16, 3), 256, 0, stream>>>(w, wh);

    // 2) fused QKV projection: [16384][1024] x [3072][1024]^T
    gemm256<3><<<dim3(12, 64, 1), 512, 131072, stream>>>(
        xh, wh, ws, 1024, 1024, 1024, 0L, 0L, 0L, 0, 1.0f);

    // 3) scores = Q * K^T * 0.125 -> sp fp16 (per batch)
    gemm256<0><<<dim3(8, 8, 8), 512, 131072, stream>>>(
        qh, kh, sp, 1024, 1024, 1024, 2097152L, 2097152L, 4194304L, 2048, 0.125f);

    // 4) softmax rows in place (8*2048 rows)
    softmax_inplace<<<16384, 256, 0, stream>>>(sp);

    // 5) out = P * V  (B operand = V^T rows, f32 output)
    gemm256<2><<<dim3(4, 8, 8), 512, 131072, stream>>>(
        sp, vt, out, 2048, 2048, 2048, 4194304L, 2097152L, 2097152L, 1024, 1.0f);
}

// Round 5
// 303.112 us; speedup vs baseline: 2.1276x; 1.0466x over previous
//
#include <hip/hip_runtime.h>

typedef _Float16 f16;
typedef f16 f16x8 __attribute__((ext_vector_type(8)));
typedef f16 f16x4 __attribute__((ext_vector_type(4)));
typedef float f32x4 __attribute__((ext_vector_type(4)));

#define GLD_LDS16(g, l) __builtin_amdgcn_global_load_lds( \
    (const __attribute__((address_space(1))) void*)(g),   \
    (__attribute__((address_space(3))) void*)(l), 16, 0, 0)

__device__ __forceinline__ void bar() {
    asm volatile("" ::: "memory");
    __builtin_amdgcn_s_barrier();
    asm volatile("" ::: "memory");
}
#define WAIT_VM(n) { asm volatile("s_waitcnt vmcnt(" #n ")" ::: "memory"); \
                     __builtin_amdgcn_sched_barrier(0); }
#define LGKM(n)    { asm volatile("s_waitcnt lgkmcnt(" #n ")" ::: "memory"); \
                     __builtin_amdgcn_sched_barrier(0); }

// ---------------------------------------------------------------------------
__global__ __launch_bounds__(256) void cast_x_kernel(const float* __restrict__ x,
                                                     f16* __restrict__ xh) {
    long i = ((long)blockIdx.x * 256 + threadIdx.x) * 8;
    float4 a = *(const float4*)&x[i];
    float4 b = *(const float4*)&x[i + 4];
    f16x8 v;
    v[0] = (f16)a.x; v[1] = (f16)a.y; v[2] = (f16)a.z; v[3] = (f16)a.w;
    v[4] = (f16)b.x; v[5] = (f16)b.y; v[6] = (f16)b.z; v[7] = (f16)b.w;
    *(f16x8*)&xh[i] = v;
}

// cast + transpose weights: W[i][d][o] f32 -> WT[i][o][d] fp16 (64x64 tiles)
__global__ __launch_bounds__(256) void cast_transpose_w(const float* __restrict__ W,
                                                        f16* __restrict__ WT) {
    __shared__ float tile[64][65];
    const int iz = blockIdx.z;
    const int d0 = blockIdx.y * 64;
    const int o0 = blockIdx.x * 64;
    const float* Wi = W + (long)iz * 1024 * 1024;
    f16* WTi = WT + (long)iz * 1024 * 1024;
    const int t = threadIdx.x;
#pragma unroll
    for (int j = 0; j < 4; ++j) {
        int idx = t + j * 256;
        int r = idx >> 4;
        int c4 = (idx & 15) * 4;
        float4 v = *(const float4*)&Wi[(long)(d0 + r) * 1024 + o0 + c4];
        tile[r][c4 + 0] = v.x; tile[r][c4 + 1] = v.y;
        tile[r][c4 + 2] = v.z; tile[r][c4 + 3] = v.w;
    }
    __syncthreads();
#pragma unroll
    for (int j = 0; j < 2; ++j) {
        int idx = t + j * 256;
        int ol = idx >> 3;
        int c8 = (idx & 7) * 8;
        f16x8 v;
#pragma unroll
        for (int e = 0; e < 8; ++e) v[e] = (f16)tile[c8 + e][ol];
        *(f16x8*)&WTi[(long)(o0 + ol) * 1024 + d0 + c8] = v;
    }
}

// ---------------------------------------------------------------------------
// 256x256 tile, BK=64, 8-phase schedule (T2+T3+T4+T5), 512 threads = 8 waves
// (2 m-waves x 4 n-waves), per-wave output 128x64, LDS 128 KiB ring.
// XCD-aware block swizzle (T1): per-z wg counts are all %8==0 here.
//
// MODE 0: scores epilogue: C fp16 = exp(acc*scale - 4)  (unnormalized softmax)
// MODE 2: PV epilogue: C f32 = acc * dinv[batch_row]
// MODE 3: fused QKV epilogue: cols [0,1024)->Q, [1024,2048)->K,
//         [2048,3072)->V^T [b][o][s]. Cv = ws base.
template <int MODE>
__global__ __launch_bounds__(512, 2)
void gemm256(const f16* __restrict__ A, const f16* __restrict__ B,
             void* __restrict__ Cv, const float* __restrict__ dinv,
             int lda, int ldb, int K,
             long sA, long sB, long sC, int ldc, float scale) {
    extern __shared__ __align__(16) char smem[];
    const int tid = threadIdx.x;
    const int lane = tid & 63;
    const int wave = tid >> 6;
    const int wm = wave >> 2;          // 0..1
    const int wn = wave & 3;           // 0..3
    const int z = blockIdx.z;

    // ---- T1: XCD-aware swizzle of (x,y); nwg%8==0 for all our launches,
    // and gridDim.x*gridDim.y%8==0 keeps z-slices XCD-aligned.
    const int o_ = blockIdx.x + gridDim.x * blockIdx.y;
    const int nwg = gridDim.x * gridDim.y;
    const int sw = (o_ & 7) * (nwg >> 3) + (o_ >> 3);
    const int bx = sw % gridDim.x;
    const int by = sw / gridDim.x;

    const long m_base = (long)by * 256;
    const long n_base = (long)bx * 256;
    const f16* Ab = A + (long)z * sA;
    const f16* Bb = B + (long)z * sB;

    // ---- staging geometry: 1024 chunks of 16B per half-tile, 2 per thread
    const int c_r0 = tid >> 3;                             // rows 0..63 (li=0)
    const int c_col = ((tid & 7) * 8) ^ ((c_r0 & 7) << 3); // inverse-swizzled col
    const long oA0 = (m_base + c_r0) * (long)lda + c_col;
    const long oA1 = oA0 + 64L * lda;                      // li=1: rows 64..127
    const long oB0 = (n_base + c_r0) * (long)ldb + c_col;
    const long oB1 = oB0 + 64L * ldb;

#define ST_A0(bf_, kt_) { long k0_ = (long)(kt_) * 64; \
    char* d_ = smem + (bf_) * 65536 + tid * 16; \
    GLD_LDS16(Ab + oA0 + k0_, d_); GLD_LDS16(Ab + oA1 + k0_, d_ + 8192); }
#define ST_A1(bf_, kt_) { long k0_ = (long)(kt_) * 64 + 128L * lda; \
    char* d_ = smem + (bf_) * 65536 + 16384 + tid * 16; \
    GLD_LDS16(Ab + oA0 + k0_, d_); GLD_LDS16(Ab + oA1 + k0_, d_ + 8192); }
#define ST_B0(bf_, kt_) { long k0_ = (long)(kt_) * 64; \
    char* d_ = smem + (bf_) * 65536 + 32768 + tid * 16; \
    GLD_LDS16(Bb + oB0 + k0_, d_); GLD_LDS16(Bb + oB1 + k0_, d_ + 8192); }
#define ST_B1(bf_, kt_) { long k0_ = (long)(kt_) * 64 + 128L * ldb; \
    char* d_ = smem + (bf_) * 65536 + 49152 + tid * 16; \
    GLD_LDS16(Bb + oB0 + k0_, d_); GLD_LDS16(Bb + oB1 + k0_, d_ + 8192); }

    // ---- fragment read offsets (swizzled)
    const int fr = lane & 15;
    const int rq = lane >> 4;
    const int cs0 = (rq * 16) ^ ((lane & 7) << 4);
    const int cs1 = cs0 ^ 64;
    const int aoff = wm * 16384 + fr * 128;
    const int boff = 32768 + (wn >> 1) * 16384 + (wn & 1) * 8192 + fr * 128;

    f32x4 acc[8][4];
#pragma unroll
    for (int i = 0; i < 8; ++i)
#pragma unroll
        for (int j = 0; j < 4; ++j) acc[i][j] = (f32x4){0.f, 0.f, 0.f, 0.f};

    const int NT = K >> 6;   // K-tiles of 64 (NT >= 16 for our shapes)

    // ---- prologue: K0 all 4 halves, then K1 B0,B1,A0
    ST_B0(0, 0); ST_B1(0, 0); ST_A0(0, 0); ST_A1(0, 0);
    WAIT_VM(4);
    ST_B0(1, 1); ST_B1(1, 1); ST_A0(1, 1);
    WAIT_VM(6);
    bar();

    for (int j = 0; j < NT; ++j) {
        char* bufb = smem + (j & 1) * 65536;
        const char* Ap = bufb + aoff;
        const char* Bp = bufb + boff;
        f16x8 af[4][2], bf[4][2];

        // ---------- phase 1
        // issue order pinned: af(8) -> bf01(4) -> bf23(4); lgkmcnt(4) then
        // covers exactly {af, bf01} (DS returns retire in order).
#pragma unroll
        for (int i = 0; i < 4; ++i) {
            af[i][0] = *(const f16x8*)(Ap + i * 2048 + cs0);
            af[i][1] = *(const f16x8*)(Ap + i * 2048 + cs1);
        }
        __builtin_amdgcn_sched_barrier(0);
#pragma unroll
        for (int ni = 0; ni < 2; ++ni) {
            bf[ni][0] = *(const f16x8*)(Bp + ni * 2048 + cs0);
            bf[ni][1] = *(const f16x8*)(Bp + ni * 2048 + cs1);
        }
        __builtin_amdgcn_sched_barrier(0);
#pragma unroll
        for (int ni = 2; ni < 4; ++ni) {
            bf[ni][0] = *(const f16x8*)(Bp + ni * 2048 + cs0);
            bf[ni][1] = *(const f16x8*)(Bp + ni * 2048 + cs1);
        }
        if (j + 1 < NT) ST_A1((j + 1) & 1, j + 1);
        bar();
        LGKM(4);
        __builtin_amdgcn_s_setprio(1);
#pragma unroll
        for (int ks = 0; ks < 2; ++ks)
#pragma unroll
            for (int i = 0; i < 4; ++i)
#pragma unroll
                for (int n = 0; n < 2; ++n)
                    acc[i][n] = __builtin_amdgcn_mfma_f32_16x16x32_f16(
                        af[i][ks], bf[n][ks], acc[i][n], 0, 0, 0);
        __builtin_amdgcn_s_setprio(0);
        bar();

        // ---------- phase 2
        LGKM(0);   // bf23 retired -> safe to overwrite B0 slot
        if (j + 2 < NT) ST_B0(j & 1, j + 2);
        bar();
        __builtin_amdgcn_s_setprio(1);
#pragma unroll
        for (int ks = 0; ks < 2; ++ks)
#pragma unroll
            for (int i = 0; i < 4; ++i)
#pragma unroll
                for (int n = 0; n < 2; ++n)
                    acc[i][2 + n] = __builtin_amdgcn_mfma_f32_16x16x32_f16(
                        af[i][ks], bf[2 + n][ks], acc[i][2 + n], 0, 0, 0);
        __builtin_amdgcn_s_setprio(0);
        bar();

        // ---------- phase 3
#pragma unroll
        for (int i = 0; i < 4; ++i) {
            af[i][0] = *(const f16x8*)(Ap + (4 + i) * 2048 + cs0);
            af[i][1] = *(const f16x8*)(Ap + (4 + i) * 2048 + cs1);
        }
        if (j + 2 < NT) ST_B1(j & 1, j + 2);
        bar();
        LGKM(0);
        __builtin_amdgcn_s_setprio(1);
#pragma unroll
        for (int ks = 0; ks < 2; ++ks)
#pragma unroll
            for (int i = 0; i < 4; ++i)
#pragma unroll
                for (int n = 0; n < 2; ++n)
                    acc[4 + i][n] = __builtin_amdgcn_mfma_f32_16x16x32_f16(
                        af[i][ks], bf[n][ks], acc[4 + i][n], 0, 0, 0);
        __builtin_amdgcn_s_setprio(0);
        bar();

        // ---------- phase 4
        if (j + 2 < NT) {
            ST_A0(j & 1, j + 2);
            WAIT_VM(6);
        } else if (j + 1 < NT) {
            WAIT_VM(0);
        }
        bar();
        __builtin_amdgcn_s_setprio(1);
#pragma unroll
        for (int ks = 0; ks < 2; ++ks)
#pragma unroll
            for (int i = 0; i < 4; ++i)
#pragma unroll
                for (int n = 0; n < 2; ++n)
                    acc[4 + i][2 + n] = __builtin_amdgcn_mfma_f32_16x16x32_f16(
                        af[i][ks], bf[2 + n][ks], acc[4 + i][2 + n], 0, 0, 0);
        __builtin_amdgcn_s_setprio(0);
        bar();
    }

    // ---- epilogue: C/D layout col = lane&15, row = (lane>>4)*4 + jj
#pragma unroll
    for (int mi = 0; mi < 8; ++mi) {
        long r0 = m_base + wm * 128 + mi * 16 + rq * 4;
#pragma unroll
        for (int ni = 0; ni < 4; ++ni) {
            long c = n_base + wn * 64 + ni * 16 + fr;
            if constexpr (MODE == 0) {
                f16* C = (f16*)Cv + (long)z * sC;
#pragma unroll
                for (int jj = 0; jj < 4; ++jj)
                    C[(r0 + jj) * (long)ldc + c] =
                        (f16)__expf(acc[mi][ni][jj] * scale - 4.0f);
            } else if constexpr (MODE == 2) {
                float* C = (float*)Cv + (long)z * sC;
#pragma unroll
                for (int jj = 0; jj < 4; ++jj)
                    C[(r0 + jj) * (long)ldc + c] =
                        acc[mi][ni][jj] * dinv[(long)z * 2048 + r0 + jj];
            } else {  // MODE 3: fused QKV
                f16* W = (f16*)Cv;
                if (c < 2048) {
                    f16* C = W + (c >> 10) * 16777216L + (c & 1023);
#pragma unroll
                    for (int jj = 0; jj < 4; ++jj)
                        C[(r0 + jj) * 1024L] = (f16)acc[mi][ni][jj];
                } else {
                    long o = c - 2048;
                    long b = r0 >> 11;
                    long s = r0 & 2047;
                    f16x4 v;
#pragma unroll
                    for (int jj = 0; jj < 4; ++jj) v[jj] = (f16)acc[mi][ni][jj];
                    *(f16x4*)&W[33554432L + b * 2097152L + o * 2048L + s] = v;
                }
            }
        }
    }
#undef ST_A0
#undef ST_A1
#undef ST_B0
#undef ST_B1
}

// ---------------------------------------------------------------------------
// per-row sum of E (fp16 [16384][2048]) -> dinv[row] = 1/sum (f32)
__global__ __launch_bounds__(256) void rowsum_inv(const f16* __restrict__ E,
                                                  float* __restrict__ dinv) {
    const f16* p = E + (long)blockIdx.x * 2048;
    const int t = threadIdx.x;
    const int lane = t & 63;
    const int wv = t >> 6;
    __shared__ float red[4];

    f16x8 v = *(const f16x8*)&p[t * 8];
    float s = 0.f;
#pragma unroll
    for (int e = 0; e < 8; ++e) s += (float)v[e];
#pragma unroll
    for (int o = 32; o; o >>= 1) s += __shfl_xor(s, o);
    if (lane == 0) red[wv] = s;
    __syncthreads();
    if (t == 0) dinv[blockIdx.x] = 1.f / (red[0] + red[1] + red[2] + red[3]);
}

// ---------------------------------------------------------------------------
extern "C" void kernel_launch(void* const* d_in, const int* in_sizes, int n_in,
                              void* d_out, int out_size, void* d_ws, size_t ws_size,
                              hipStream_t stream) {
    const float* x = (const float*)d_in[0];    // [8,2048,1024]
    const float* w = (const float*)d_in[1];    // [3,1024,1024]
    float* out = (float*)d_out;                // [8,2048,1024] f32
    char* ws = (char*)d_ws;

    // workspace layout (bytes); sp overlaps dead xh/wh regions
    f16* qh = (f16*)(ws + 0);            // 32 MB  [8*2048][1024]  (Q; dead after scores)
    f16* kh = (f16*)(ws + 33554432);     // 32 MB  (K)
    f16* vt = (f16*)(ws + 67108864);     // 32 MB  [8][1024][2048] (V^T)
    f16* xh = (f16*)(ws + 100663296);    // 32 MB  (dead after QKV gemm)
    f16* wh = (f16*)(ws + 134217728);    // 6 MB   W^T fp16 [3072][1024]
    f16* sp = (f16*)(ws + 100663296);    // 64 MB  E = exp(scores-4) [8][2048][2048]
    float* dinv = (float*)(ws + 0);      // 64 KB  (overlays dead Q)

    // 1) casts
    cast_x_kernel<<<8192, 256, 0, stream>>>(x, xh);
    cast_transpose_w<<<dim3(16, 16, 3), 256, 0, stream>>>(w, wh);

    // 2) fused QKV projection: [16384][1024] x [3072][1024]^T
    gemm256<3><<<dim3(12, 64, 1), 512, 131072, stream>>>(
        xh, wh, ws, nullptr, 1024, 1024, 1024, 0L, 0L, 0L, 0, 1.0f);

    // 3) E = exp(Q*K^T*0.125 - 4) -> sp fp16 (per batch)
    gemm256<0><<<dim3(8, 8, 8), 512, 131072, stream>>>(
        qh, kh, sp, nullptr, 1024, 1024, 1024, 2097152L, 2097152L, 4194304L, 2048, 0.125f);

    // 4) dinv[row] = 1 / rowsum(E)
    rowsum_inv<<<16384, 256, 0, stream>>>(sp, dinv);

    // 5) out = (E * V) * dinv  (B operand = V^T rows, f32 output)
    gemm256<2><<<dim3(4, 8, 8), 512, 131072, stream>>>(
        sp, vt, out, dinv, 2048, 2048, 2048, 4194304L, 2097152L, 2097152L, 1024, 1.0f);
}